// Round 1
// 318.568 us; speedup vs baseline: 1.0199x; 1.0199x over previous
//
#include <hip/hip_runtime.h>
#include <math.h>

#define QDIM 4096
#define NQ 12
#define QBATCH 2048

typedef _Float16 f16x8 __attribute__((ext_vector_type(8)));
typedef float f32x4 __attribute__((ext_vector_type(4)));
typedef int i32x4 __attribute__((ext_vector_type(4)));

__device__ __forceinline__ void gld_lds16(const void* gptr, void* ldsptr) {
    __builtin_amdgcn_global_load_lds(
        (const __attribute__((address_space(1))) void*)gptr,
        (__attribute__((address_space(3))) void*)ldsptr,
        16, 0, 0);
}

__device__ __forceinline__ int q8(float x) {
    float y = fminf(fmaxf(x, -127.f), 127.f);
    return (int)rintf(y);
}
__device__ __forceinline__ int pack4_i8(int a, int b, int c, int d) {
    return (a & 0xFF) | ((b & 0xFF) << 8) | ((c & 0xFF) << 16) | ((d & 0xFF) << 24);
}

// ---------------------------------------------------------------------------
// conv (single pass over E): Eh = f16(E) [both halves];
// G8[n,:] = int8( (c0*E[n,:]+c1*E[n+2048,:]) * 127/6 )   (G ~ N(0,1), 6-sigma clip)
// ---------------------------------------------------------------------------
__global__ __launch_bounds__(256) void conv_kernel(
    const float* __restrict__ E, const float* __restrict__ wgt,
    _Float16* __restrict__ Eh, signed char* __restrict__ G8)
{
    float th = 0.5f * (wgt[0] + wgt[1] + wgt[2]);
    float c0 = cosf(th), c1 = -sinf(th);
    const float qs = 127.f / 6.f;
    size_t flat = ((size_t)blockIdx.x * 256 + threadIdx.x) * 8;  // [0, 2048*4096)
    size_t n = flat >> 12;
    size_t k = flat & (QDIM - 1);
    const float* p0 = E + n * QDIM + k;
    const float* p1 = p0 + (size_t)QBATCH * QDIM;
    float4 a0 = ((const float4*)p0)[0], a1 = ((const float4*)p0)[1];
    float4 b0 = ((const float4*)p1)[0], b1 = ((const float4*)p1)[1];
    f16x8 h0 = { (_Float16)a0.x, (_Float16)a0.y, (_Float16)a0.z, (_Float16)a0.w,
                 (_Float16)a1.x, (_Float16)a1.y, (_Float16)a1.z, (_Float16)a1.w };
    f16x8 h1 = { (_Float16)b0.x, (_Float16)b0.y, (_Float16)b0.z, (_Float16)b0.w,
                 (_Float16)b1.x, (_Float16)b1.y, (_Float16)b1.z, (_Float16)b1.w };
    *(f16x8*)&Eh[n * QDIM + k] = h0;
    *(f16x8*)&Eh[(n + QBATCH) * QDIM + k] = h1;
    float g[8] = { c0*a0.x + c1*b0.x, c0*a0.y + c1*b0.y, c0*a0.z + c1*b0.z, c0*a0.w + c1*b0.w,
                   c0*a1.x + c1*b1.x, c0*a1.y + c1*b1.y, c0*a1.z + c1*b1.z, c0*a1.w + c1*b1.w };
    int2 gp = { pack4_i8(q8(g[0]*qs), q8(g[1]*qs), q8(g[2]*qs), q8(g[3]*qs)),
                pack4_i8(q8(g[4]*qs), q8(g[5]*qs), q8(g[6]*qs), q8(g[7]*qs)) };
    *(int2*)&G8[n * QDIM + k] = gp;
}

// ---------------------------------------------------------------------------
// Expand: A1[b,idx]=f16(Re v), A1[b+2048,idx]=f16(Im v). Prefix over top 8 bits.
// Also zeroes out[b] (gemm2 accumulates atomically later in the stream).
// ---------------------------------------------------------------------------
__global__ __launch_bounds__(256) void expand_kernel(
    const float* __restrict__ inputs, _Float16* __restrict__ A1,
    float* __restrict__ out)
{
    __shared__ float ab[NQ][4];
    const int b = blockIdx.x;
    const int tid = threadIdx.x;
    if (tid == 0) out[b] = 0.f;
    if (tid < NQ) {
        float x = inputs[b * NQ + tid];
        float ry = 0.5f * x;
        float rz = 0.5f * x * x;
        float ca = cosf(ry), sa = sinf(ry), cz = cosf(rz), sz = sinf(rz);
        ab[tid][0] = ca * cz;  ab[tid][1] = -ca * sz;
        ab[tid][2] = sa * cz;  ab[tid][3] =  sa * sz;
    }
    __syncthreads();
    float pr0 = 1.f, pi0 = 0.f;
#pragma unroll
    for (int q = 0; q < 8; ++q) {
        int bit = (tid >> (7 - q)) & 1;
        float cr = ab[q][bit * 2 + 0], ci = ab[q][bit * 2 + 1];
        float nr = pr0 * cr - pi0 * ci;
        float ni = pr0 * ci + pi0 * cr;
        pr0 = nr; pi0 = ni;
    }
    f16x8 vr[2], vi[2];
#pragma unroll
    for (int u = 0; u < 16; ++u) {
        float pr = pr0, pi = pi0;
#pragma unroll
        for (int q = 8; q < 12; ++q) {
            int bit = (u >> (11 - q)) & 1;
            float cr = ab[q][bit * 2 + 0], ci = ab[q][bit * 2 + 1];
            float nr = pr * cr - pi * ci;
            float ni = pr * ci + pi * cr;
            pr = nr; pi = ni;
        }
        vr[u >> 3][u & 7] = (_Float16)pr;
        vi[u >> 3][u & 7] = (_Float16)pi;
    }
    const int idx0 = tid * 16;
    *(f16x8*)&A1[(size_t)b * QDIM + idx0] = vr[0];
    *(f16x8*)&A1[(size_t)b * QDIM + idx0 + 8] = vr[1];
    *(f16x8*)&A1[(size_t)(b + QBATCH) * QDIM + idx0] = vi[0];
    *(f16x8*)&A1[(size_t)(b + QBATCH) * QDIM + idx0 + 8] = vi[1];
}

// ---------------------------------------------------------------------------
// GEMM1 v2: 256x256 tile, BK=64, 8 waves (2M x 4N), double-buffered 128KiB LDS,
// 4-phase schedule with counted vmcnt (never 0 in main loop), raw s_barrier,
// setprio around MFMA clusters, cross-phase ds_read pipelining.
// Same proven XOR-granule swizzle (0 bank conflicts) and MFMA fragment layout.
//
// Per K-tile t (buf d=t&1), staging tile t+1 into e=d^1:
//   ph1: STG B'n0,n1 ; vmcnt(2) [lands A(t)n1,n3] ; rd b1(d) ; BAR ;
//        MFMA Q00(a0,b0) ; BAR
//   ph2: STG B'n2,n3 ; rd a1(d) ; BAR ; MFMA Q01(a0,b1) ; BAR
//   ph3: STG A'n0,n2 ; BAR ; MFMA Q11(a1,b1) ; BAR
//   ph4: STG A'n1,n3 ; vmcnt(2) [lands B' full + A'n0,n2] ; BAR ;
//        MFMA Q10(a1,b0) ; rd a0(e),b0(e) ; BAR
// Reads of tile tau span ph4(tau-1)..ph2(tau); overwrites of its buffer are
// issued >= 2 barrier-separated phases later -> race-free (verified on paper).
// ---------------------------------------------------------------------------
#define VMCNT(N_) asm volatile("s_waitcnt vmcnt(" #N_ ")" ::: "memory")
#define SBAR()                              \
    do {                                    \
        asm volatile("" ::: "memory");      \
        __builtin_amdgcn_s_barrier();       \
        asm volatile("" ::: "memory");      \
    } while (0)

__global__ __launch_bounds__(512, 2) void gemm_f16_256(
    const _Float16* __restrict__ A, const _Float16* __restrict__ B,
    _Float16* __restrict__ C, int N)
{
    const int K = QDIM;
    __shared__ __attribute__((aligned(16))) _Float16 As[2][256 * 64];
    __shared__ __attribute__((aligned(16))) _Float16 Bs[2][256 * 64];

    const int tid  = threadIdx.x;
    const int wave = tid >> 6;
    const int lane = tid & 63;
    const int bm0 = blockIdx.y * 256;
    const int bn0 = blockIdx.x * 256;
    const int wm0 = (wave >> 2) * 128;   // 0 or 128
    const int wn0 = (wave & 3) * 64;     // 0,64,128,192
    const int q = lane >> 4;
    const int r = lane & 15;
    const int rx = r & 7;

    f32x4 acc[8][4];
#pragma unroll
    for (int i = 0; i < 8; ++i)
#pragma unroll
        for (int j = 0; j < 4; ++j) acc[i][j] = (f32x4){0.f, 0.f, 0.f, 0.f};

    // Staging geometry: one gld_lds16 instr = 512 thr x 16B = 64 rows of 64 f16.
    // Instr NN covers tile rows [NN*64, NN*64+64). Thread: row=NN*64+(tid>>3),
    // LDS granule tid&7; global source granule pre-swizzled by ^(row&7) so the
    // linear LDS landing matches the swizzled read layout (involution).
    const int srow = tid >> 3;
    const int scol = ((tid & 7) ^ (srow & 7)) * 8;
    const _Float16* gA = A + (size_t)(bm0 + srow) * K + scol;
    const _Float16* gB = B + (size_t)(bn0 + srow) * K + scol;

#define STG_A(D, KK, NN) gld_lds16(gA + (size_t)(NN) * 64 * K + (KK), &As[D][(NN) * 4096 + wave * 512])
#define STG_B(D, KK, NN) gld_lds16(gB + (size_t)(NN) * 64 * K + (KK), &Bs[D][(NN) * 4096 + wave * 512])

#define RD_A4(DST, D, IB)                                                          \
    _Pragma("unroll")                                                              \
    for (int ii = 0; ii < 4; ++ii) {                                               \
        _Pragma("unroll")                                                          \
        for (int ss = 0; ss < 2; ++ss)                                             \
            DST[ii][ss] = *(const f16x8*)&As[D][(wm0 + ((IB) + ii) * 16 + r) * 64  \
                                                + (((ss * 4 + q) ^ rx) * 8)];      \
    }
#define RD_B2(DST, D, JB)                                                          \
    _Pragma("unroll")                                                              \
    for (int jj = 0; jj < 2; ++jj) {                                               \
        _Pragma("unroll")                                                          \
        for (int ss = 0; ss < 2; ++ss)                                             \
            DST[jj][ss] = *(const f16x8*)&Bs[D][(wn0 + ((JB) + jj) * 16 + r) * 64  \
                                                + (((ss * 4 + q) ^ rx) * 8)];      \
    }
#define MM8(AR, BR, I0, J0)                                                        \
    _Pragma("unroll")                                                              \
    for (int ii = 0; ii < 4; ++ii) {                                               \
        _Pragma("unroll")                                                          \
        for (int jj = 0; jj < 2; ++jj) {                                           \
            acc[(I0) + ii][(J0) + jj] = __builtin_amdgcn_mfma_f32_16x16x32_f16(    \
                AR[ii][0], BR[jj][0], acc[(I0) + ii][(J0) + jj], 0, 0, 0);         \
            acc[(I0) + ii][(J0) + jj] = __builtin_amdgcn_mfma_f32_16x16x32_f16(    \
                AR[ii][1], BR[jj][1], acc[(I0) + ii][(J0) + jj], 0, 0, 0);         \
        }                                                                          \
    }

    f16x8 a0[4][2], a1[4][2], b0[2][2], b1[2][2];

    // Prologue: stage tile 0 fully into buf 0, drain once, preload Q00 frags.
    STG_B(0, 0, 0); STG_B(0, 0, 1); STG_B(0, 0, 2); STG_B(0, 0, 3);
    STG_A(0, 0, 0); STG_A(0, 0, 2); STG_A(0, 0, 1); STG_A(0, 0, 3);
    VMCNT(0);
    SBAR();
    RD_A4(a0, 0, 0);
    RD_B2(b0, 0, 0);

    for (int t = 0; t < 64; ++t) {
        const int d = t & 1;
        const int e = d ^ 1;
        const int kn = ((t + 1) & 63) * 64;  // wraps to 0 on last iter (harmless reload)

        // ---- ph1 ----
        STG_B(e, kn, 0); STG_B(e, kn, 1);
        VMCNT(2);                 // lands A(t) n1,n3 (read in ph2 below)
        RD_B2(b1, d, 2);
        SBAR();
        __builtin_amdgcn_s_setprio(1);
        MM8(a0, b0, 0, 0);        // Q00
        __builtin_amdgcn_s_setprio(0);
        SBAR();

        // ---- ph2 ----
        STG_B(e, kn, 2); STG_B(e, kn, 3);
        RD_A4(a1, d, 4);
        SBAR();
        __builtin_amdgcn_s_setprio(1);
        MM8(a0, b1, 0, 2);        // Q01
        __builtin_amdgcn_s_setprio(0);
        SBAR();

        // ---- ph3 ----
        STG_A(e, kn, 0); STG_A(e, kn, 2);
        SBAR();
        __builtin_amdgcn_s_setprio(1);
        MM8(a1, b1, 4, 2);        // Q11
        __builtin_amdgcn_s_setprio(0);
        SBAR();

        // ---- ph4 ----
        STG_A(e, kn, 1); STG_A(e, kn, 3);
        VMCNT(2);                 // lands B(t+1) full + A(t+1) n0,n2
        SBAR();
        __builtin_amdgcn_s_setprio(1);
        MM8(a1, b0, 4, 0);        // Q10 (uses old b0 before it is reloaded)
        __builtin_amdgcn_s_setprio(0);
        RD_A4(a0, e, 0);          // next tile's Q00 fragments
        RD_B2(b0, e, 0);
        SBAR();
    }

    // Epilogue: C/D layout col=r, row=q*4+reg (proven).
#pragma unroll
    for (int i = 0; i < 8; ++i) {
        const int crow = bm0 + wm0 + i * 16 + q * 4;
#pragma unroll
        for (int rr = 0; rr < 4; ++rr)
#pragma unroll
            for (int j = 0; j < 4; ++j)
                C[(size_t)(crow + rr) * N + bn0 + wn0 + j * 16 + r] = (_Float16)acc[i][j][rr];
    }
#undef STG_A
#undef STG_B
#undef RD_A4
#undef RD_B2
#undef MM8
}

// ---------------------------------------------------------------------------
// Butterfly v2 (3-phase register FFT): u2 = R u1 per complex row.
// idx = a*256 + b*16 + c. Phase A: stages on c-bits (in-reg, thread=(a,b)).
// Exchange via padded LDS pos = 273a + 17b + c (<=2-way banks on most sets).
// Phase B: stages on b-bits (thread=(a,c)). Phase C: stages on a-bits
// (thread=(b,c)); absmax reduce from regs; direct coalesced i8 byte stores.
// ---------------------------------------------------------------------------
__global__ __launch_bounds__(256) void butterfly_kernel(
    const _Float16* __restrict__ u1, const float* __restrict__ wgt,
    signed char* __restrict__ A2, float* __restrict__ scaleA)
{
    __shared__ float sRe[4366];
    __shared__ float sIm[4366];
    __shared__ float mats[NQ][8];
    __shared__ float red[8];
    const int blk = blockIdx.x;
    const int tid = threadIdx.x;
    const int ah = tid >> 4;    // phase A/B: a  | phase C: b
    const int al = tid & 15;    // phase A: b    | phase B/C: c

    if (tid < NQ) {
        float tx = 0.5f * wgt[3 + tid];
        float tz = 0.5f * wgt[15 + tid];
        float c = cosf(tx), s = sinf(tx), cz = cosf(tz), sz = sinf(tz);
        mats[tid][0] =  c * cz;  mats[tid][1] = -c * sz;
        mats[tid][2] =  s * sz;  mats[tid][3] = -s * cz;
        mats[tid][4] = -s * sz;  mats[tid][5] = -s * cz;
        mats[tid][6] =  c * cz;  mats[tid][7] =  c * sz;
    }

    // load 16 consecutive elements (idx = tid*16 + c)
    float xr[16], xi[16];
    {
        const _Float16* pRe = u1 + (size_t)blk * QDIM + tid * 16;
        const _Float16* pIm = u1 + (size_t)(blk + QBATCH) * QDIM + tid * 16;
        f16x8 r0 = ((const f16x8*)pRe)[0], r1 = ((const f16x8*)pRe)[1];
        f16x8 i0 = ((const f16x8*)pIm)[0], i1 = ((const f16x8*)pIm)[1];
#pragma unroll
        for (int j = 0; j < 8; ++j) {
            xr[j] = (float)r0[j]; xr[8 + j] = (float)r1[j];
            xi[j] = (float)i0[j]; xi[8 + j] = (float)i1[j];
        }
    }
    __syncthreads();  // mats ready

#define BFLY_STAGE(arrR, arrI, K_, Q_)                                         \
    {                                                                          \
        const float m00r = mats[Q_][0], m00i = mats[Q_][1];                    \
        const float m01r = mats[Q_][2], m01i = mats[Q_][3];                    \
        const float m10r = mats[Q_][4], m10i = mats[Q_][5];                    \
        const float m11r = mats[Q_][6], m11i = mats[Q_][7];                    \
        _Pragma("unroll")                                                      \
        for (int t = 0; t < 8; ++t) {                                          \
            int i0 = ((t >> (K_)) << ((K_) + 1)) | (t & ((1 << (K_)) - 1));    \
            int i1 = i0 | (1 << (K_));                                         \
            float x0r = arrR[i0], x0i = arrI[i0];                              \
            float x1r = arrR[i1], x1i = arrI[i1];                              \
            arrR[i0] = m00r * x0r - m00i * x0i + m01r * x1r - m01i * x1i;      \
            arrI[i0] = m00r * x0i + m00i * x0r + m01r * x1i + m01i * x1r;      \
            arrR[i1] = m10r * x0r - m10i * x0i + m11r * x1r - m11i * x1i;      \
            arrI[i1] = m10r * x0i + m10i * x0r + m11r * x1i + m11i * x1r;      \
        }                                                                      \
    }

    // Phase A: idx bits 0..3 (c), qubits 11..8
#pragma unroll
    for (int p = 0; p < 4; ++p) BFLY_STAGE(xr, xi, p, 11 - p);

    // Exchange 1: thread (a=ah, b=al) writes its c-line
#pragma unroll
    for (int c = 0; c < 16; ++c) {
        sRe[273 * ah + 17 * al + c] = xr[c];
        sIm[273 * ah + 17 * al + c] = xi[c];
    }
    __syncthreads();

    // Phase B: thread (a=ah, c=al) reads b-line; stages on idx bits 4..7
    float yr[16], yi[16];
#pragma unroll
    for (int b = 0; b < 16; ++b) {
        yr[b] = sRe[273 * ah + 17 * b + al];
        yi[b] = sIm[273 * ah + 17 * b + al];
    }
#pragma unroll
    for (int p = 0; p < 4; ++p) BFLY_STAGE(yr, yi, p, 7 - p);

    // Exchange 2: same positions this thread read — no barrier needed before write
#pragma unroll
    for (int b = 0; b < 16; ++b) {
        sRe[273 * ah + 17 * b + al] = yr[b];
        sIm[273 * ah + 17 * b + al] = yi[b];
    }
    __syncthreads();

    // Phase C: thread (b=ah, c=al) reads a-line; stages on idx bits 8..11
    float zr[16], zi[16];
#pragma unroll
    for (int a = 0; a < 16; ++a) {
        zr[a] = sRe[273 * a + 17 * ah + al];
        zi[a] = sIm[273 * a + 17 * ah + al];
    }
#pragma unroll
    for (int p = 0; p < 4; ++p) BFLY_STAGE(zr, zi, p, 3 - p);

    // per-row absmax from registers
    float mR = 0.f, mI = 0.f;
#pragma unroll
    for (int j = 0; j < 16; ++j) {
        mR = fmaxf(mR, fabsf(zr[j]));
        mI = fmaxf(mI, fabsf(zi[j]));
    }
#pragma unroll
    for (int off = 32; off > 0; off >>= 1) {
        mR = fmaxf(mR, __shfl_xor(mR, off, 64));
        mI = fmaxf(mI, __shfl_xor(mI, off, 64));
    }
    const int wid = tid >> 6;
    if ((tid & 63) == 0) { red[wid] = mR; red[4 + wid] = mI; }
    __syncthreads();
    mR = fmaxf(fmaxf(red[0], red[1]), fmaxf(red[2], red[3]));
    mI = fmaxf(fmaxf(red[4], red[5]), fmaxf(red[6], red[7]));
    mR = fmaxf(mR, 1e-30f);
    mI = fmaxf(mI, 1e-30f);
    if (tid == 0) {
        scaleA[blk] = mR / 127.f;
        scaleA[blk + QBATCH] = mI / 127.f;
    }
    const float invR = 127.f / mR, invI = 127.f / mI;

    // store: element idx = a*256 + ah*16 + al -> per-a instr covers 64
    // consecutive bytes per wave (coalesced byte stores)
    signed char* oRe = A2 + (size_t)blk * QDIM + ah * 16 + al;
    signed char* oIm = A2 + (size_t)(blk + QBATCH) * QDIM + ah * 16 + al;
#pragma unroll
    for (int a = 0; a < 16; ++a) {
        oRe[a * 256] = (signed char)q8(zr[a] * invR);
        oIm[a * 256] = (signed char)q8(zi[a] * invI);
    }
#undef BFLY_STAGE
}

// ---------------------------------------------------------------------------
// GEMM2 (i8, fused reduce): acc[m,n] = sum_k A2[m,k]*G8[n,k] (i32);
// out[m & 2047] += sum_n (acc * scaleA[m] * dqG)^2.  Same tile/swizzle as gemm_f16,
// two mfma_i32_16x16x64_i8 per fragment pair per 128B stage.
// ---------------------------------------------------------------------------
__global__ __launch_bounds__(256) void gemm2_i8(
    const signed char* __restrict__ A, const signed char* __restrict__ B,
    const float* __restrict__ scaleA, float* __restrict__ out)
{
    const int K = QDIM;  // bytes per row
    __shared__ __attribute__((aligned(16))) signed char As[128 * 128];
    __shared__ __attribute__((aligned(16))) signed char Bs[128 * 128];

    const int tid  = threadIdx.x;
    const int wave = tid >> 6;
    const int lane = tid & 63;
    const int bn0 = blockIdx.x * 128;
    const int bm0 = blockIdx.y * 128;
    const int wm = (wave >> 1) * 64;
    const int wn = (wave & 1) * 64;
    const int q = lane >> 4;
    const int r = lane & 15;
    const int rx = r & 7;

    i32x4 acc[4][4];
#pragma unroll
    for (int i = 0; i < 4; ++i)
#pragma unroll
        for (int j = 0; j < 4; ++j) acc[i][j] = (i32x4){0, 0, 0, 0};

    const signed char* gA[4];
    const signed char* gB[4];
    char* lA[4];
    char* lB[4];
#pragma unroll
    for (int n = 0; n < 4; ++n) {
        int c = n * 256 + tid;
        int row = c >> 3;
        int gcol = (c & 7) ^ (row & 7);
        gA[n] = A + (size_t)(bm0 + row) * K + gcol * 16;
        gB[n] = B + (size_t)(bn0 + row) * K + gcol * 16;
        lA[n] = (char*)As + (n * 256 + wave * 64) * 16;
        lB[n] = (char*)Bs + (n * 256 + wave * 64) * 16;
    }

    for (int kk = 0; kk < K; kk += 128) {
#pragma unroll
        for (int n = 0; n < 4; ++n) {
            gld_lds16(gA[n] + kk, lA[n]);
            gld_lds16(gB[n] + kk, lB[n]);
        }
        __syncthreads();

#pragma unroll
        for (int s = 0; s < 2; ++s) {
            i32x4 af[4], bf[4];
#pragma unroll
            for (int i = 0; i < 4; ++i) {
                int row = wm + i * 16 + r;
                af[i] = *(const i32x4*)&As[row * 128 + (((s * 4 + q) ^ rx) * 16)];
            }
#pragma unroll
            for (int j = 0; j < 4; ++j) {
                int row = wn + j * 16 + r;
                bf[j] = *(const i32x4*)&Bs[row * 128 + (((s * 4 + q) ^ rx) * 16)];
            }
#pragma unroll
            for (int i = 0; i < 4; ++i)
#pragma unroll
                for (int j = 0; j < 4; ++j)
                    acc[i][j] = __builtin_amdgcn_mfma_i32_16x16x64_i8(af[i], bf[j], acc[i][j], 0, 0, 0);
        }
        __syncthreads();
    }

    // C/D layout: col = r, row = q*4 + reg. Fused |.|^2 reduce.
    const float dqG = 6.f / 127.f;
#pragma unroll
    for (int i = 0; i < 4; ++i) {
#pragma unroll
        for (int rr = 0; rr < 4; ++rr) {
            const int row = bm0 + wm + i * 16 + q * 4 + rr;
            const float sc = scaleA[row] * dqG;
            float v = 0.f;
#pragma unroll
            for (int j = 0; j < 4; ++j) {
                float t = sc * (float)acc[i][j][rr];
                v = fmaf(t, t, v);
            }
            v += __shfl_xor(v, 1, 64);
            v += __shfl_xor(v, 2, 64);
            v += __shfl_xor(v, 4, 64);
            v += __shfl_xor(v, 8, 64);
            if (r == 0) atomicAdd(&out[row & (QBATCH - 1)], v);
        }
    }
}

// ---------------------------------------------------------------------------
extern "C" void kernel_launch(void* const* d_in, const int* in_sizes, int n_in,
                              void* d_out, int out_size, void* d_ws, size_t ws_size,
                              hipStream_t stream)
{
    const float* inputs = (const float*)d_in[0];   // [2048, 12]
    const float* weight = (const float*)d_in[1];   // [27]
    const float* E      = (const float*)d_in[2];   // [4096, 4096] fp32
    float* out = (float*)d_out;                    // [2048]

    char* ws = (char*)d_ws;
    const size_t MB = 1024 * 1024;
    _Float16*    Eh     = (_Float16*)   (ws + 0);         // 32 MB f16 [4096][4096]
    signed char* G8     = (signed char*)(ws + 32 * MB);   //  8 MB i8  [2048][4096]
    _Float16*    A1     = (_Float16*)   (ws + 40 * MB);   // 32 MB f16 [4096][4096]
    _Float16*    u1     = (_Float16*)   (ws + 72 * MB);   // 32 MB f16 [4096][4096]
    signed char* A2     = (signed char*)(ws + 104 * MB);  // 16 MB i8  [4096][4096]
    float*       scaleA = (float*)      (ws + 120 * MB);  // 16 KB

    conv_kernel<<<(QBATCH * QDIM / 8) / 256, 256, 0, stream>>>(E, weight, Eh, G8);
    expand_kernel<<<QBATCH, 256, 0, stream>>>(inputs, A1, out);
    // u1 = v @ Eh^T  (M=4096 Re/Im stacked, N=4096, K=4096), f16, 256^2 8-wave
    gemm_f16_256<<<dim3(QDIM / 256, QDIM / 256), 512, 0, stream>>>(A1, Eh, u1, QDIM);
    // u2 = R u1 -> int8 rows + per-row scales (3-phase register FFT)
    butterfly_kernel<<<QBATCH, 256, 0, stream>>>(u1, weight, A2, scaleA);
    // out[b] = sum_n |(u2 @ G^T)[b / b+2048, n]|^2  (i8 MFMA, fused reduce)
    gemm2_i8<<<dim3(2048 / 128, QDIM / 128), 256, 0, stream>>>(A2, G8, scaleA, out);
}

// Round 2
// 313.480 us; speedup vs baseline: 1.0365x; 1.0162x over previous
//
#include <hip/hip_runtime.h>
#include <math.h>

#define QDIM 4096
#define NQ 12
#define QBATCH 2048

typedef _Float16 f16x8 __attribute__((ext_vector_type(8)));
typedef float f32x4 __attribute__((ext_vector_type(4)));
typedef int i32x4 __attribute__((ext_vector_type(4)));

__device__ __forceinline__ void gld_lds16(const void* gptr, void* ldsptr) {
    __builtin_amdgcn_global_load_lds(
        (const __attribute__((address_space(1))) void*)gptr,
        (__attribute__((address_space(3))) void*)ldsptr,
        16, 0, 0);
}

__device__ __forceinline__ int q8(float x) {
    float y = fminf(fmaxf(x, -127.f), 127.f);
    return (int)rintf(y);
}
__device__ __forceinline__ int pack4_i8(int a, int b, int c, int d) {
    return (a & 0xFF) | ((b & 0xFF) << 8) | ((c & 0xFF) << 16) | ((d & 0xFF) << 24);
}

// ---------------------------------------------------------------------------
// conv (single pass over E): Eh = f16(E) [both halves];
// G8[n,:] = int8( (c0*E[n,:]+c1*E[n+2048,:]) * 127/6 )   (G ~ N(0,1), 6-sigma clip)
// ---------------------------------------------------------------------------
__global__ __launch_bounds__(256) void conv_kernel(
    const float* __restrict__ E, const float* __restrict__ wgt,
    _Float16* __restrict__ Eh, signed char* __restrict__ G8)
{
    float th = 0.5f * (wgt[0] + wgt[1] + wgt[2]);
    float c0 = cosf(th), c1 = -sinf(th);
    const float qs = 127.f / 6.f;
    size_t flat = ((size_t)blockIdx.x * 256 + threadIdx.x) * 8;  // [0, 2048*4096)
    size_t n = flat >> 12;
    size_t k = flat & (QDIM - 1);
    const float* p0 = E + n * QDIM + k;
    const float* p1 = p0 + (size_t)QBATCH * QDIM;
    float4 a0 = ((const float4*)p0)[0], a1 = ((const float4*)p0)[1];
    float4 b0 = ((const float4*)p1)[0], b1 = ((const float4*)p1)[1];
    f16x8 h0 = { (_Float16)a0.x, (_Float16)a0.y, (_Float16)a0.z, (_Float16)a0.w,
                 (_Float16)a1.x, (_Float16)a1.y, (_Float16)a1.z, (_Float16)a1.w };
    f16x8 h1 = { (_Float16)b0.x, (_Float16)b0.y, (_Float16)b0.z, (_Float16)b0.w,
                 (_Float16)b1.x, (_Float16)b1.y, (_Float16)b1.z, (_Float16)b1.w };
    *(f16x8*)&Eh[n * QDIM + k] = h0;
    *(f16x8*)&Eh[(n + QBATCH) * QDIM + k] = h1;
    float g[8] = { c0*a0.x + c1*b0.x, c0*a0.y + c1*b0.y, c0*a0.z + c1*b0.z, c0*a0.w + c1*b0.w,
                   c0*a1.x + c1*b1.x, c0*a1.y + c1*b1.y, c0*a1.z + c1*b1.z, c0*a1.w + c1*b1.w };
    int2 gp = { pack4_i8(q8(g[0]*qs), q8(g[1]*qs), q8(g[2]*qs), q8(g[3]*qs)),
                pack4_i8(q8(g[4]*qs), q8(g[5]*qs), q8(g[6]*qs), q8(g[7]*qs)) };
    *(int2*)&G8[n * QDIM + k] = gp;
}

// ---------------------------------------------------------------------------
// Expand: A1[b,idx]=f16(Re v), A1[b+2048,idx]=f16(Im v). Prefix over top 8 bits.
// Also zeroes out[b] (gemm2 accumulates atomically later in the stream).
// ---------------------------------------------------------------------------
__global__ __launch_bounds__(256) void expand_kernel(
    const float* __restrict__ inputs, _Float16* __restrict__ A1,
    float* __restrict__ out)
{
    __shared__ float ab[NQ][4];
    const int b = blockIdx.x;
    const int tid = threadIdx.x;
    if (tid == 0) out[b] = 0.f;
    if (tid < NQ) {
        float x = inputs[b * NQ + tid];
        float ry = 0.5f * x;
        float rz = 0.5f * x * x;
        float ca = cosf(ry), sa = sinf(ry), cz = cosf(rz), sz = sinf(rz);
        ab[tid][0] = ca * cz;  ab[tid][1] = -ca * sz;
        ab[tid][2] = sa * cz;  ab[tid][3] =  sa * sz;
    }
    __syncthreads();
    float pr0 = 1.f, pi0 = 0.f;
#pragma unroll
    for (int q = 0; q < 8; ++q) {
        int bit = (tid >> (7 - q)) & 1;
        float cr = ab[q][bit * 2 + 0], ci = ab[q][bit * 2 + 1];
        float nr = pr0 * cr - pi0 * ci;
        float ni = pr0 * ci + pi0 * cr;
        pr0 = nr; pi0 = ni;
    }
    f16x8 vr[2], vi[2];
#pragma unroll
    for (int u = 0; u < 16; ++u) {
        float pr = pr0, pi = pi0;
#pragma unroll
        for (int q = 8; q < 12; ++q) {
            int bit = (u >> (11 - q)) & 1;
            float cr = ab[q][bit * 2 + 0], ci = ab[q][bit * 2 + 1];
            float nr = pr * cr - pi * ci;
            float ni = pr * ci + pi * cr;
            pr = nr; pi = ni;
        }
        vr[u >> 3][u & 7] = (_Float16)pr;
        vi[u >> 3][u & 7] = (_Float16)pi;
    }
    const int idx0 = tid * 16;
    *(f16x8*)&A1[(size_t)b * QDIM + idx0] = vr[0];
    *(f16x8*)&A1[(size_t)b * QDIM + idx0 + 8] = vr[1];
    *(f16x8*)&A1[(size_t)(b + QBATCH) * QDIM + idx0] = vi[0];
    *(f16x8*)&A1[(size_t)(b + QBATCH) * QDIM + idx0 + 8] = vi[1];
}

// ---------------------------------------------------------------------------
// GEMM1 v3: 256x256 tile, BK=64, 8 waves (2M x 4N), double-buffered 128KiB LDS,
// DEEP 4-phase schedule: every counted-vmcnt drain targets loads issued >=4
// phases earlier (v2 drained 1-phase-old loads -> raw latency stall, neutral).
//
// Steady-state FIFO invariant entering tile t (buf d=t&1): 8 outstanding =
//   [A(t)1,3 | A(t+1)0,2 | B(t+1)0..3]   (oldest -> newest)
// Iteration t issues:
//   ph1: STG A(t+1)n1,n3 (buf e)         read t+1.ph2   (5-phase slack)
//   ph2: VMCNT(8) [drains A(t)1,3, 5ph]; STG A(t+2)n0,n2 (buf d)
//   ph3: STG B(t+2)n0,n1 (buf d)
//   ph4: STG B(t+2)n2,n3 (buf d); VMCNT(8) [drains A(t+1)0,2 + B(t+1)0..3,
//        youngest 4ph]; preload a0,b0 of tile t+1 from buf e
// Overwrite hazards: each staged region's last ds_read completes (lgkmcnt
// before its consuming MFMA) >=2 s_barriers before the overwriting STG issues.
// Wrap loads at t=62,63 are redundant but keep vmcnt math uniform.
// ---------------------------------------------------------------------------
#define VMCNT(N_) asm volatile("s_waitcnt vmcnt(" #N_ ")" ::: "memory")
#define SBAR()                              \
    do {                                    \
        asm volatile("" ::: "memory");      \
        __builtin_amdgcn_s_barrier();       \
        asm volatile("" ::: "memory");      \
    } while (0)

__global__ __launch_bounds__(512, 2) void gemm_f16_256(
    const _Float16* __restrict__ A, const _Float16* __restrict__ B,
    _Float16* __restrict__ C, int N)
{
    const int K = QDIM;
    __shared__ __attribute__((aligned(16))) _Float16 As[2][256 * 64];
    __shared__ __attribute__((aligned(16))) _Float16 Bs[2][256 * 64];

    const int tid  = threadIdx.x;
    const int wave = tid >> 6;
    const int lane = tid & 63;
    const int bm0 = blockIdx.y * 256;
    const int bn0 = blockIdx.x * 256;
    const int wm0 = (wave >> 2) * 128;   // 0 or 128
    const int wn0 = (wave & 3) * 64;     // 0,64,128,192
    const int q = lane >> 4;
    const int r = lane & 15;
    const int rx = r & 7;

    f32x4 acc[8][4];
#pragma unroll
    for (int i = 0; i < 8; ++i)
#pragma unroll
        for (int j = 0; j < 4; ++j) acc[i][j] = (f32x4){0.f, 0.f, 0.f, 0.f};

    // Staging geometry: one gld_lds16 instr = 512 thr x 16B = 64 rows of 64 f16.
    // Chunk NN covers tile rows [NN*64, NN*64+64). Global source granule is
    // pre-swizzled by ^(row&7) so the linear LDS landing matches the swizzled
    // read layout (involution; both-sides rule).
    const int srow = tid >> 3;
    const int scol = ((tid & 7) ^ (srow & 7)) * 8;
    const _Float16* gA = A + (size_t)(bm0 + srow) * K + scol;
    const _Float16* gB = B + (size_t)(bn0 + srow) * K + scol;

#define STG_A(D, KK, NN) gld_lds16(gA + (size_t)(NN) * 64 * K + (KK), &As[D][(NN) * 4096 + wave * 512])
#define STG_B(D, KK, NN) gld_lds16(gB + (size_t)(NN) * 64 * K + (KK), &Bs[D][(NN) * 4096 + wave * 512])

#define RD_A4(DST, D, IB)                                                          \
    _Pragma("unroll")                                                              \
    for (int ii = 0; ii < 4; ++ii) {                                               \
        _Pragma("unroll")                                                          \
        for (int ss = 0; ss < 2; ++ss)                                             \
            DST[ii][ss] = *(const f16x8*)&As[D][(wm0 + ((IB) + ii) * 16 + r) * 64  \
                                                + (((ss * 4 + q) ^ rx) * 8)];      \
    }
#define RD_B2(DST, D, JB)                                                          \
    _Pragma("unroll")                                                              \
    for (int jj = 0; jj < 2; ++jj) {                                               \
        _Pragma("unroll")                                                          \
        for (int ss = 0; ss < 2; ++ss)                                             \
            DST[jj][ss] = *(const f16x8*)&Bs[D][(wn0 + ((JB) + jj) * 16 + r) * 64  \
                                                + (((ss * 4 + q) ^ rx) * 8)];      \
    }
#define MM8(AR, BR, I0, J0)                                                        \
    _Pragma("unroll")                                                              \
    for (int ii = 0; ii < 4; ++ii) {                                               \
        _Pragma("unroll")                                                          \
        for (int jj = 0; jj < 2; ++jj) {                                           \
            acc[(I0) + ii][(J0) + jj] = __builtin_amdgcn_mfma_f32_16x16x32_f16(    \
                AR[ii][0], BR[jj][0], acc[(I0) + ii][(J0) + jj], 0, 0, 0);         \
            acc[(I0) + ii][(J0) + jj] = __builtin_amdgcn_mfma_f32_16x16x32_f16(    \
                AR[ii][1], BR[jj][1], acc[(I0) + ii][(J0) + jj], 0, 0, 0);         \
        }                                                                          \
    }

    f16x8 a0[4][2], a1[4][2], b0[2][2], b1[2][2];

    // Prologue: 14 loads in exact steady-state FIFO order; drain to 8.
    // Landed after VMCNT(8): A(0)0,2 + B(0)0..3 (what the preload reads).
    // Outstanding: [A(0)1,3, A(1)0,2, B(1)0..3] — the loop invariant at t=0.
    STG_A(0, 0, 0); STG_A(0, 0, 2);
    STG_B(0, 0, 0); STG_B(0, 0, 1); STG_B(0, 0, 2); STG_B(0, 0, 3);
    STG_A(0, 0, 1); STG_A(0, 0, 3);
    STG_A(1, 64, 0); STG_A(1, 64, 2);
    STG_B(1, 64, 0); STG_B(1, 64, 1); STG_B(1, 64, 2); STG_B(1, 64, 3);
    VMCNT(8);
    SBAR();
    RD_A4(a0, 0, 0);
    RD_B2(b0, 0, 0);

    for (int t = 0; t < 64; ++t) {
        const int d = t & 1;
        const int e = d ^ 1;
        const int k1 = ((t + 1) & 63) * 64;
        const int k2 = ((t + 2) & 63) * 64;

        // ---- ph1 ----
        STG_A(e, k1, 1); STG_A(e, k1, 3);
        RD_B2(b1, d, 2);          // B(t) rows wn0+32..63
        SBAR();
        __builtin_amdgcn_s_setprio(1);
        MM8(a0, b0, 0, 0);        // Q00
        __builtin_amdgcn_s_setprio(0);
        SBAR();

        // ---- ph2 ----
        VMCNT(8);                 // drains A(t)1,3 (issued t-1.ph1; 5-ph slack)
        STG_A(d, k2, 0); STG_A(d, k2, 2);
        RD_A4(a1, d, 4);          // A(t) rows wm0+64..127
        SBAR();
        __builtin_amdgcn_s_setprio(1);
        MM8(a0, b1, 0, 2);        // Q01
        __builtin_amdgcn_s_setprio(0);
        SBAR();

        // ---- ph3 ----
        STG_B(d, k2, 0); STG_B(d, k2, 1);
        SBAR();
        __builtin_amdgcn_s_setprio(1);
        MM8(a1, b1, 4, 2);        // Q11
        __builtin_amdgcn_s_setprio(0);
        SBAR();

        // ---- ph4 ----
        STG_B(d, k2, 2); STG_B(d, k2, 3);
        VMCNT(8);                 // drains A(t+1)0,2 + B(t+1)0..3 (4-6 ph slack)
        SBAR();
        RD_A4(a0, e, 0);          // next tile's a0 (not an input of Q10)
        __builtin_amdgcn_s_setprio(1);
        MM8(a1, b0, 4, 0);        // Q10 (consumes old b0 regs)
        __builtin_amdgcn_s_setprio(0);
        RD_B2(b0, e, 0);          // reload b0 after its last use
        SBAR();
    }
    VMCNT(0);                     // drain in-flight LDS DMA before LDS goes dead

    // Epilogue: C/D layout col=r, row=q*4+reg (proven).
#pragma unroll
    for (int i = 0; i < 8; ++i) {
        const int crow = bm0 + wm0 + i * 16 + q * 4;
#pragma unroll
        for (int rr = 0; rr < 4; ++rr)
#pragma unroll
            for (int j = 0; j < 4; ++j)
                C[(size_t)(crow + rr) * N + bn0 + wn0 + j * 16 + r] = (_Float16)acc[i][j][rr];
    }
#undef STG_A
#undef STG_B
#undef RD_A4
#undef RD_B2
#undef MM8
}

// ---------------------------------------------------------------------------
// Butterfly v2 (3-phase register FFT): u2 = R u1 per complex row.
// idx = a*256 + b*16 + c. Phase A: stages on c-bits (in-reg, thread=(a,b)).
// Exchange via padded LDS pos = 273a + 17b + c (<=2-way banks on most sets).
// Phase B: stages on b-bits (thread=(a,c)). Phase C: stages on a-bits
// (thread=(b,c)); absmax reduce from regs; direct coalesced i8 byte stores.
// ---------------------------------------------------------------------------
__global__ __launch_bounds__(256) void butterfly_kernel(
    const _Float16* __restrict__ u1, const float* __restrict__ wgt,
    signed char* __restrict__ A2, float* __restrict__ scaleA)
{
    __shared__ float sRe[4366];
    __shared__ float sIm[4366];
    __shared__ float mats[NQ][8];
    __shared__ float red[8];
    const int blk = blockIdx.x;
    const int tid = threadIdx.x;
    const int ah = tid >> 4;    // phase A/B: a  | phase C: b
    const int al = tid & 15;    // phase A: b    | phase B/C: c

    if (tid < NQ) {
        float tx = 0.5f * wgt[3 + tid];
        float tz = 0.5f * wgt[15 + tid];
        float c = cosf(tx), s = sinf(tx), cz = cosf(tz), sz = sinf(tz);
        mats[tid][0] =  c * cz;  mats[tid][1] = -c * sz;
        mats[tid][2] =  s * sz;  mats[tid][3] = -s * cz;
        mats[tid][4] = -s * sz;  mats[tid][5] = -s * cz;
        mats[tid][6] =  c * cz;  mats[tid][7] =  c * sz;
    }

    // load 16 consecutive elements (idx = tid*16 + c)
    float xr[16], xi[16];
    {
        const _Float16* pRe = u1 + (size_t)blk * QDIM + tid * 16;
        const _Float16* pIm = u1 + (size_t)(blk + QBATCH) * QDIM + tid * 16;
        f16x8 r0 = ((const f16x8*)pRe)[0], r1 = ((const f16x8*)pRe)[1];
        f16x8 i0 = ((const f16x8*)pIm)[0], i1 = ((const f16x8*)pIm)[1];
#pragma unroll
        for (int j = 0; j < 8; ++j) {
            xr[j] = (float)r0[j]; xr[8 + j] = (float)r1[j];
            xi[j] = (float)i0[j]; xi[8 + j] = (float)i1[j];
        }
    }
    __syncthreads();  // mats ready

#define BFLY_STAGE(arrR, arrI, K_, Q_)                                         \
    {                                                                          \
        const float m00r = mats[Q_][0], m00i = mats[Q_][1];                    \
        const float m01r = mats[Q_][2], m01i = mats[Q_][3];                    \
        const float m10r = mats[Q_][4], m10i = mats[Q_][5];                    \
        const float m11r = mats[Q_][6], m11i = mats[Q_][7];                    \
        _Pragma("unroll")                                                      \
        for (int t = 0; t < 8; ++t) {                                          \
            int i0 = ((t >> (K_)) << ((K_) + 1)) | (t & ((1 << (K_)) - 1));    \
            int i1 = i0 | (1 << (K_));                                         \
            float x0r = arrR[i0], x0i = arrI[i0];                              \
            float x1r = arrR[i1], x1i = arrI[i1];                              \
            arrR[i0] = m00r * x0r - m00i * x0i + m01r * x1r - m01i * x1i;      \
            arrI[i0] = m00r * x0i + m00i * x0r + m01r * x1i + m01i * x1r;      \
            arrR[i1] = m10r * x0r - m10i * x0i + m11r * x1r - m11i * x1i;      \
            arrI[i1] = m10r * x0i + m10i * x0r + m11r * x1i + m11i * x1r;      \
        }                                                                      \
    }

    // Phase A: idx bits 0..3 (c), qubits 11..8
#pragma unroll
    for (int p = 0; p < 4; ++p) BFLY_STAGE(xr, xi, p, 11 - p);

    // Exchange 1: thread (a=ah, b=al) writes its c-line
#pragma unroll
    for (int c = 0; c < 16; ++c) {
        sRe[273 * ah + 17 * al + c] = xr[c];
        sIm[273 * ah + 17 * al + c] = xi[c];
    }
    __syncthreads();

    // Phase B: thread (a=ah, c=al) reads b-line; stages on idx bits 4..7
    float yr[16], yi[16];
#pragma unroll
    for (int b = 0; b < 16; ++b) {
        yr[b] = sRe[273 * ah + 17 * b + al];
        yi[b] = sIm[273 * ah + 17 * b + al];
    }
#pragma unroll
    for (int p = 0; p < 4; ++p) BFLY_STAGE(yr, yi, p, 7 - p);

    // Exchange 2: same positions this thread read — no barrier needed before write
#pragma unroll
    for (int b = 0; b < 16; ++b) {
        sRe[273 * ah + 17 * b + al] = yr[b];
        sIm[273 * ah + 17 * b + al] = yi[b];
    }
    __syncthreads();

    // Phase C: thread (b=ah, c=al) reads a-line; stages on idx bits 8..11
    float zr[16], zi[16];
#pragma unroll
    for (int a = 0; a < 16; ++a) {
        zr[a] = sRe[273 * a + 17 * ah + al];
        zi[a] = sIm[273 * a + 17 * ah + al];
    }
#pragma unroll
    for (int p = 0; p < 4; ++p) BFLY_STAGE(zr, zi, p, 3 - p);

    // per-row absmax from registers
    float mR = 0.f, mI = 0.f;
#pragma unroll
    for (int j = 0; j < 16; ++j) {
        mR = fmaxf(mR, fabsf(zr[j]));
        mI = fmaxf(mI, fabsf(zi[j]));
    }
#pragma unroll
    for (int off = 32; off > 0; off >>= 1) {
        mR = fmaxf(mR, __shfl_xor(mR, off, 64));
        mI = fmaxf(mI, __shfl_xor(mI, off, 64));
    }
    const int wid = tid >> 6;
    if ((tid & 63) == 0) { red[wid] = mR; red[4 + wid] = mI; }
    __syncthreads();
    mR = fmaxf(fmaxf(red[0], red[1]), fmaxf(red[2], red[3]));
    mI = fmaxf(fmaxf(red[4], red[5]), fmaxf(red[6], red[7]));
    mR = fmaxf(mR, 1e-30f);
    mI = fmaxf(mI, 1e-30f);
    if (tid == 0) {
        scaleA[blk] = mR / 127.f;
        scaleA[blk + QBATCH] = mI / 127.f;
    }
    const float invR = 127.f / mR, invI = 127.f / mI;

    // store: element idx = a*256 + ah*16 + al -> per-a instr covers 64
    // consecutive bytes per wave (coalesced byte stores)
    signed char* oRe = A2 + (size_t)blk * QDIM + ah * 16 + al;
    signed char* oIm = A2 + (size_t)(blk + QBATCH) * QDIM + ah * 16 + al;
#pragma unroll
    for (int a = 0; a < 16; ++a) {
        oRe[a * 256] = (signed char)q8(zr[a] * invR);
        oIm[a * 256] = (signed char)q8(zi[a] * invI);
    }
#undef BFLY_STAGE
}

// ---------------------------------------------------------------------------
// GEMM2 (i8, fused reduce): acc[m,n] = sum_k A2[m,k]*G8[n,k] (i32);
// out[m & 2047] += sum_n (acc * scaleA[m] * dqG)^2.  Same tile/swizzle as gemm_f16,
// two mfma_i32_16x16x64_i8 per fragment pair per 128B stage.
// ---------------------------------------------------------------------------
__global__ __launch_bounds__(256) void gemm2_i8(
    const signed char* __restrict__ A, const signed char* __restrict__ B,
    const float* __restrict__ scaleA, float* __restrict__ out)
{
    const int K = QDIM;  // bytes per row
    __shared__ __attribute__((aligned(16))) signed char As[128 * 128];
    __shared__ __attribute__((aligned(16))) signed char Bs[128 * 128];

    const int tid  = threadIdx.x;
    const int wave = tid >> 6;
    const int lane = tid & 63;
    const int bn0 = blockIdx.x * 128;
    const int bm0 = blockIdx.y * 128;
    const int wm = (wave >> 1) * 64;
    const int wn = (wave & 1) * 64;
    const int q = lane >> 4;
    const int r = lane & 15;
    const int rx = r & 7;

    i32x4 acc[4][4];
#pragma unroll
    for (int i = 0; i < 4; ++i)
#pragma unroll
        for (int j = 0; j < 4; ++j) acc[i][j] = (i32x4){0, 0, 0, 0};

    const signed char* gA[4];
    const signed char* gB[4];
    char* lA[4];
    char* lB[4];
#pragma unroll
    for (int n = 0; n < 4; ++n) {
        int c = n * 256 + tid;
        int row = c >> 3;
        int gcol = (c & 7) ^ (row & 7);
        gA[n] = A + (size_t)(bm0 + row) * K + gcol * 16;
        gB[n] = B + (size_t)(bn0 + row) * K + gcol * 16;
        lA[n] = (char*)As + (n * 256 + wave * 64) * 16;
        lB[n] = (char*)Bs + (n * 256 + wave * 64) * 16;
    }

    for (int kk = 0; kk < K; kk += 128) {
#pragma unroll
        for (int n = 0; n < 4; ++n) {
            gld_lds16(gA[n] + kk, lA[n]);
            gld_lds16(gB[n] + kk, lB[n]);
        }
        __syncthreads();

#pragma unroll
        for (int s = 0; s < 2; ++s) {
            i32x4 af[4], bf[4];
#pragma unroll
            for (int i = 0; i < 4; ++i) {
                int row = wm + i * 16 + r;
                af[i] = *(const i32x4*)&As[row * 128 + (((s * 4 + q) ^ rx) * 16)];
            }
#pragma unroll
            for (int j = 0; j < 4; ++j) {
                int row = wn + j * 16 + r;
                bf[j] = *(const i32x4*)&Bs[row * 128 + (((s * 4 + q) ^ rx) * 16)];
            }
#pragma unroll
            for (int i = 0; i < 4; ++i)
#pragma unroll
                for (int j = 0; j < 4; ++j)
                    acc[i][j] = __builtin_amdgcn_mfma_i32_16x16x64_i8(af[i], bf[j], acc[i][j], 0, 0, 0);
        }
        __syncthreads();
    }

    // C/D layout: col = r, row = q*4 + reg. Fused |.|^2 reduce.
    const float dqG = 6.f / 127.f;
#pragma unroll
    for (int i = 0; i < 4; ++i) {
#pragma unroll
        for (int rr = 0; rr < 4; ++rr) {
            const int row = bm0 + wm + i * 16 + q * 4 + rr;
            const float sc = scaleA[row] * dqG;
            float v = 0.f;
#pragma unroll
            for (int j = 0; j < 4; ++j) {
                float t = sc * (float)acc[i][j][rr];
                v = fmaf(t, t, v);
            }
            v += __shfl_xor(v, 1, 64);
            v += __shfl_xor(v, 2, 64);
            v += __shfl_xor(v, 4, 64);
            v += __shfl_xor(v, 8, 64);
            if (r == 0) atomicAdd(&out[row & (QBATCH - 1)], v);
        }
    }
}

// ---------------------------------------------------------------------------
extern "C" void kernel_launch(void* const* d_in, const int* in_sizes, int n_in,
                              void* d_out, int out_size, void* d_ws, size_t ws_size,
                              hipStream_t stream)
{
    const float* inputs = (const float*)d_in[0];   // [2048, 12]
    const float* weight = (const float*)d_in[1];   // [27]
    const float* E      = (const float*)d_in[2];   // [4096, 4096] fp32
    float* out = (float*)d_out;                    // [2048]

    char* ws = (char*)d_ws;
    const size_t MB = 1024 * 1024;
    _Float16*    Eh     = (_Float16*)   (ws + 0);         // 32 MB f16 [4096][4096]
    signed char* G8     = (signed char*)(ws + 32 * MB);   //  8 MB i8  [2048][4096]
    _Float16*    A1     = (_Float16*)   (ws + 40 * MB);   // 32 MB f16 [4096][4096]
    _Float16*    u1     = (_Float16*)   (ws + 72 * MB);   // 32 MB f16 [4096][4096]
    signed char* A2     = (signed char*)(ws + 104 * MB);  // 16 MB i8  [4096][4096]
    float*       scaleA = (float*)      (ws + 120 * MB);  // 16 KB

    conv_kernel<<<(QBATCH * QDIM / 8) / 256, 256, 0, stream>>>(E, weight, Eh, G8);
    expand_kernel<<<QBATCH, 256, 0, stream>>>(inputs, A1, out);
    // u1 = v @ Eh^T  (M=4096 Re/Im stacked, N=4096, K=4096), f16, 256^2 8-wave
    gemm_f16_256<<<dim3(QDIM / 256, QDIM / 256), 512, 0, stream>>>(A1, Eh, u1, QDIM);
    // u2 = R u1 -> int8 rows + per-row scales (3-phase register FFT)
    butterfly_kernel<<<QBATCH, 256, 0, stream>>>(u1, weight, A2, scaleA);
    // out[b] = sum_n |(u2 @ G^T)[b / b+2048, n]|^2  (i8 MFMA, fused reduce)
    gemm2_i8<<<dim3(2048 / 128, QDIM / 128), 256, 0, stream>>>(A2, G8, scaleA, out);
}

// Round 3
// 299.006 us; speedup vs baseline: 1.0867x; 1.0484x over previous
//
#include <hip/hip_runtime.h>
#include <math.h>

#define QDIM 4096
#define NQ 12
#define QBATCH 2048

typedef _Float16 f16x8 __attribute__((ext_vector_type(8)));
typedef float f32x4 __attribute__((ext_vector_type(4)));
typedef int i32x4 __attribute__((ext_vector_type(4)));

__device__ __forceinline__ void gld_lds16(const void* gptr, void* ldsptr) {
    __builtin_amdgcn_global_load_lds(
        (const __attribute__((address_space(1))) void*)gptr,
        (__attribute__((address_space(3))) void*)ldsptr,
        16, 0, 0);
}

__device__ __forceinline__ int q8(float x) {
    float y = fminf(fmaxf(x, -127.f), 127.f);
    return (int)rintf(y);
}
__device__ __forceinline__ int pack4_i8(int a, int b, int c, int d) {
    return (a & 0xFF) | ((b & 0xFF) << 8) | ((c & 0xFF) << 16) | ((d & 0xFF) << 24);
}

// ---------------------------------------------------------------------------
// conv (single pass over E): Eh = f16(E) [both halves];
// G8[n,:] = int8( (c0*E[n,:]+c1*E[n+2048,:]) * 127/6 )   (G ~ N(0,1), 6-sigma clip)
// ---------------------------------------------------------------------------
__global__ __launch_bounds__(256) void conv_kernel(
    const float* __restrict__ E, const float* __restrict__ wgt,
    _Float16* __restrict__ Eh, signed char* __restrict__ G8)
{
    float th = 0.5f * (wgt[0] + wgt[1] + wgt[2]);
    float c0 = cosf(th), c1 = -sinf(th);
    const float qs = 127.f / 6.f;
    size_t flat = ((size_t)blockIdx.x * 256 + threadIdx.x) * 8;  // [0, 2048*4096)
    size_t n = flat >> 12;
    size_t k = flat & (QDIM - 1);
    const float* p0 = E + n * QDIM + k;
    const float* p1 = p0 + (size_t)QBATCH * QDIM;
    float4 a0 = ((const float4*)p0)[0], a1 = ((const float4*)p0)[1];
    float4 b0 = ((const float4*)p1)[0], b1 = ((const float4*)p1)[1];
    f16x8 h0 = { (_Float16)a0.x, (_Float16)a0.y, (_Float16)a0.z, (_Float16)a0.w,
                 (_Float16)a1.x, (_Float16)a1.y, (_Float16)a1.z, (_Float16)a1.w };
    f16x8 h1 = { (_Float16)b0.x, (_Float16)b0.y, (_Float16)b0.z, (_Float16)b0.w,
                 (_Float16)b1.x, (_Float16)b1.y, (_Float16)b1.z, (_Float16)b1.w };
    *(f16x8*)&Eh[n * QDIM + k] = h0;
    *(f16x8*)&Eh[(n + QBATCH) * QDIM + k] = h1;
    float g[8] = { c0*a0.x + c1*b0.x, c0*a0.y + c1*b0.y, c0*a0.z + c1*b0.z, c0*a0.w + c1*b0.w,
                   c0*a1.x + c1*b1.x, c0*a1.y + c1*b1.y, c0*a1.z + c1*b1.z, c0*a1.w + c1*b1.w };
    int2 gp = { pack4_i8(q8(g[0]*qs), q8(g[1]*qs), q8(g[2]*qs), q8(g[3]*qs)),
                pack4_i8(q8(g[4]*qs), q8(g[5]*qs), q8(g[6]*qs), q8(g[7]*qs)) };
    *(int2*)&G8[n * QDIM + k] = gp;
}

// ---------------------------------------------------------------------------
// Expand: A1[b,idx]=f16(Re v), A1[b+2048,idx]=f16(Im v). Prefix over top 8 bits.
// Also zeroes out[b] (gemm2 accumulates atomically later in the stream).
// ---------------------------------------------------------------------------
__global__ __launch_bounds__(256) void expand_kernel(
    const float* __restrict__ inputs, _Float16* __restrict__ A1,
    float* __restrict__ out)
{
    __shared__ float ab[NQ][4];
    const int b = blockIdx.x;
    const int tid = threadIdx.x;
    if (tid == 0) out[b] = 0.f;
    if (tid < NQ) {
        float x = inputs[b * NQ + tid];
        float ry = 0.5f * x;
        float rz = 0.5f * x * x;
        float ca = cosf(ry), sa = sinf(ry), cz = cosf(rz), sz = sinf(rz);
        ab[tid][0] = ca * cz;  ab[tid][1] = -ca * sz;
        ab[tid][2] = sa * cz;  ab[tid][3] =  sa * sz;
    }
    __syncthreads();
    float pr0 = 1.f, pi0 = 0.f;
#pragma unroll
    for (int q = 0; q < 8; ++q) {
        int bit = (tid >> (7 - q)) & 1;
        float cr = ab[q][bit * 2 + 0], ci = ab[q][bit * 2 + 1];
        float nr = pr0 * cr - pi0 * ci;
        float ni = pr0 * ci + pi0 * cr;
        pr0 = nr; pi0 = ni;
    }
    f16x8 vr[2], vi[2];
#pragma unroll
    for (int u = 0; u < 16; ++u) {
        float pr = pr0, pi = pi0;
#pragma unroll
        for (int q = 8; q < 12; ++q) {
            int bit = (u >> (11 - q)) & 1;
            float cr = ab[q][bit * 2 + 0], ci = ab[q][bit * 2 + 1];
            float nr = pr * cr - pi * ci;
            float ni = pr * ci + pi * cr;
            pr = nr; pi = ni;
        }
        vr[u >> 3][u & 7] = (_Float16)pr;
        vi[u >> 3][u & 7] = (_Float16)pi;
    }
    const int idx0 = tid * 16;
    *(f16x8*)&A1[(size_t)b * QDIM + idx0] = vr[0];
    *(f16x8*)&A1[(size_t)b * QDIM + idx0 + 8] = vr[1];
    *(f16x8*)&A1[(size_t)(b + QBATCH) * QDIM + idx0] = vi[0];
    *(f16x8*)&A1[(size_t)(b + QBATCH) * QDIM + idx0 + 8] = vi[1];
}

// ---------------------------------------------------------------------------
// GEMM1 v4: faithful port of the verified 256x256 8-phase template (m201),
// bf16 -> f16 only. BM=BN=256, BK=64, 8 waves (2Mx4N), 512 thr, 128KiB LDS
// = 2 dbuf x 4 chunks(64 rows) x 64 cols x 2 mats. Half h = chunks {2h,2h+1}.
// 2 K-steps per loop iteration, 8 self-contained phases:
//   {ds_read frags for THIS phase; stage 1 half-tile (2 gld_lds);
//    [lgkmcnt(8) if 12 reads]; barrier; lgkmcnt(0); setprio(1); 16 MFMA;
//    setprio(0); barrier}
// Stage slots (iter tau, steps s0=2tau->buf0, s1=2tau+1->buf1):
//   ph1 A0(s1) ph2 A1(s1) ph3 B0(s0+2) ph4 B1(s0+2)+VMCNT(4)
//   ph5 A0(s0+2) ph6 A1(s0+2) ph7 B0(s1+2) ph8 B1(s1+2)+VMCNT(4)
// VMCNT(4) leaves only the 2 newest halves outstanding -> every half is
// guaranteed landed >=1 phase before its first read; every stage overwrites a
// region whose last reader's lgkmcnt(0) completed >=1 barrier earlier (the
// per-phase lgkmcnt(0) doubles as the overwrite-hazard fence).
// ---------------------------------------------------------------------------
#define VMCNT(N_) asm volatile("s_waitcnt vmcnt(" #N_ ")" ::: "memory")
#define LGKM0()   asm volatile("s_waitcnt lgkmcnt(0)" ::: "memory")
#define LGKM8()   asm volatile("s_waitcnt lgkmcnt(8)" ::: "memory")
#define SBAR()                              \
    do {                                    \
        asm volatile("" ::: "memory");      \
        __builtin_amdgcn_s_barrier();       \
        asm volatile("" ::: "memory");      \
    } while (0)

__global__ __launch_bounds__(512, 2) void gemm_f16_256(
    const _Float16* __restrict__ A, const _Float16* __restrict__ B,
    _Float16* __restrict__ C, int N)
{
    const int K = QDIM;
    __shared__ __attribute__((aligned(16))) _Float16 As[2][256 * 64];
    __shared__ __attribute__((aligned(16))) _Float16 Bs[2][256 * 64];

    const int tid  = threadIdx.x;
    const int wave = tid >> 6;
    const int lane = tid & 63;
    const int bm0 = blockIdx.y * 256;
    const int bn0 = blockIdx.x * 256;
    const int wm0 = (wave >> 2) * 128;   // 0 or 128
    const int wn0 = (wave & 3) * 64;     // 0,64,128,192
    const int q = lane >> 4;
    const int r = lane & 15;
    const int rx = r & 7;

    f32x4 acc[8][4];
#pragma unroll
    for (int i = 0; i < 8; ++i)
#pragma unroll
        for (int j = 0; j < 4; ++j) acc[i][j] = (f32x4){0.f, 0.f, 0.f, 0.f};

    // Staging: one gld_lds16 = 512 thr x 16B = one 64-row chunk of 64 f16.
    // Global source granule pre-swizzled by ^(row&7) so the linear LDS landing
    // matches the swizzled read layout (involution; both-sides rule).
    const int srow = tid >> 3;
    const int scol = ((tid & 7) ^ (srow & 7)) * 8;
    const _Float16* gA = A + (size_t)(bm0 + srow) * K + scol;
    const _Float16* gB = B + (size_t)(bn0 + srow) * K + scol;

#define STG_A(D, KK, NN) gld_lds16(gA + (size_t)(NN) * 64 * K + (KK), &As[D][(NN) * 4096 + wave * 512])
#define STG_B(D, KK, NN) gld_lds16(gB + (size_t)(NN) * 64 * K + (KK), &Bs[D][(NN) * 4096 + wave * 512])
#define STG_AH(D, KK, H) do { STG_A(D, KK, 2*(H)); STG_A(D, KK, 2*(H)+1); } while (0)
#define STG_BH(D, KK, H) do { STG_B(D, KK, 2*(H)); STG_B(D, KK, 2*(H)+1); } while (0)

#define RD_A4(DST, D, IB)                                                          \
    _Pragma("unroll")                                                              \
    for (int ii = 0; ii < 4; ++ii) {                                               \
        _Pragma("unroll")                                                          \
        for (int ss = 0; ss < 2; ++ss)                                             \
            DST[ii][ss] = *(const f16x8*)&As[D][(wm0 + ((IB) + ii) * 16 + r) * 64  \
                                                + (((ss * 4 + q) ^ rx) * 8)];      \
    }
#define RD_B2(DST, D, JB)                                                          \
    _Pragma("unroll")                                                              \
    for (int jj = 0; jj < 2; ++jj) {                                               \
        _Pragma("unroll")                                                          \
        for (int ss = 0; ss < 2; ++ss)                                             \
            DST[jj][ss] = *(const f16x8*)&Bs[D][(wn0 + ((JB) + jj) * 16 + r) * 64  \
                                                + (((ss * 4 + q) ^ rx) * 8)];      \
    }
#define MM8(AR, BR, I0, J0)                                                        \
    _Pragma("unroll")                                                              \
    for (int ii = 0; ii < 4; ++ii) {                                               \
        _Pragma("unroll")                                                          \
        for (int jj = 0; jj < 2; ++jj) {                                           \
            acc[(I0) + ii][(J0) + jj] = __builtin_amdgcn_mfma_f32_16x16x32_f16(    \
                AR[ii][0], BR[jj][0], acc[(I0) + ii][(J0) + jj], 0, 0, 0);         \
            acc[(I0) + ii][(J0) + jj] = __builtin_amdgcn_mfma_f32_16x16x32_f16(    \
                AR[ii][1], BR[jj][1], acc[(I0) + ii][(J0) + jj], 0, 0, 0);         \
        }                                                                          \
    }

    f16x8 a0[4][2], a1[4][2], b0[2][2], b1[2][2];

    // Prologue: step 0 fully into buf0, then B halves of step 1 into buf1.
    // VMCNT(4) -> step-0 halves landed; outstanding FIFO = [B0(1), B1(1)],
    // which is exactly the loop invariant entering tau=0.
    STG_AH(0, 0, 0); STG_AH(0, 0, 1);
    STG_BH(0, 0, 0); STG_BH(0, 0, 1);
    STG_BH(1, 64, 0); STG_BH(1, 64, 1);
    VMCNT(4);
    SBAR();

    for (int tau = 0; tau < 32; ++tau) {
        const int k1 = (2 * tau + 1) * 64;          // step s1 (<= 63, no wrap)
        const int k2 = ((2 * tau + 2) & 63) * 64;   // wraps at tail (redundant, uniform)
        const int k3 = ((2 * tau + 3) & 63) * 64;

        // ---- ph1: Q00(s0) ----
        RD_A4(a0, 0, 0); RD_B2(b0, 0, 0);
        STG_AH(1, k1, 0);
        LGKM8();
        SBAR(); LGKM0();
        __builtin_amdgcn_s_setprio(1);
        MM8(a0, b0, 0, 0);
        __builtin_amdgcn_s_setprio(0);
        SBAR();

        // ---- ph2: Q01(s0) ----
        RD_B2(b1, 0, 2);
        STG_AH(1, k1, 1);
        SBAR(); LGKM0();
        __builtin_amdgcn_s_setprio(1);
        MM8(a0, b1, 0, 2);
        __builtin_amdgcn_s_setprio(0);
        SBAR();

        // ---- ph3: Q11(s0) ----
        RD_A4(a1, 0, 4);
        STG_BH(0, k2, 0);
        SBAR(); LGKM0();
        __builtin_amdgcn_s_setprio(1);
        MM8(a1, b1, 4, 2);
        __builtin_amdgcn_s_setprio(0);
        SBAR();

        // ---- ph4: Q10(s0) ----
        STG_BH(0, k2, 1);
        VMCNT(4);
        SBAR(); LGKM0();
        __builtin_amdgcn_s_setprio(1);
        MM8(a1, b0, 4, 0);
        __builtin_amdgcn_s_setprio(0);
        SBAR();

        // ---- ph5: Q00(s1) ----
        RD_A4(a0, 1, 0); RD_B2(b0, 1, 0);
        STG_AH(0, k2, 0);
        LGKM8();
        SBAR(); LGKM0();
        __builtin_amdgcn_s_setprio(1);
        MM8(a0, b0, 0, 0);
        __builtin_amdgcn_s_setprio(0);
        SBAR();

        // ---- ph6: Q01(s1) ----
        RD_B2(b1, 1, 2);
        STG_AH(0, k2, 1);
        SBAR(); LGKM0();
        __builtin_amdgcn_s_setprio(1);
        MM8(a0, b1, 0, 2);
        __builtin_amdgcn_s_setprio(0);
        SBAR();

        // ---- ph7: Q11(s1) ----
        RD_A4(a1, 1, 4);
        STG_BH(1, k3, 0);
        SBAR(); LGKM0();
        __builtin_amdgcn_s_setprio(1);
        MM8(a1, b1, 4, 2);
        __builtin_amdgcn_s_setprio(0);
        SBAR();

        // ---- ph8: Q10(s1) ----
        STG_BH(1, k3, 1);
        VMCNT(4);
        SBAR(); LGKM0();
        __builtin_amdgcn_s_setprio(1);
        MM8(a1, b0, 4, 0);
        __builtin_amdgcn_s_setprio(0);
        SBAR();
    }
    VMCNT(0);                     // drain redundant wrap loads before LDS dies

    // Epilogue: C/D layout col=r, row=q*4+reg (proven).
#pragma unroll
    for (int i = 0; i < 8; ++i) {
        const int crow = bm0 + wm0 + i * 16 + q * 4;
#pragma unroll
        for (int rr = 0; rr < 4; ++rr)
#pragma unroll
            for (int j = 0; j < 4; ++j)
                C[(size_t)(crow + rr) * N + bn0 + wn0 + j * 16 + r] = (_Float16)acc[i][j][rr];
    }
#undef STG_A
#undef STG_B
#undef STG_AH
#undef STG_BH
#undef RD_A4
#undef RD_B2
#undef MM8
}

// ---------------------------------------------------------------------------
// Butterfly v2 (3-phase register FFT): u2 = R u1 per complex row.
// idx = a*256 + b*16 + c. Phase A: stages on c-bits (in-reg, thread=(a,b)).
// Exchange via padded LDS pos = 273a + 17b + c (<=2-way banks on most sets).
// Phase B: stages on b-bits (thread=(a,c)). Phase C: stages on a-bits
// (thread=(b,c)); absmax reduce from regs; direct coalesced i8 byte stores.
// ---------------------------------------------------------------------------
__global__ __launch_bounds__(256) void butterfly_kernel(
    const _Float16* __restrict__ u1, const float* __restrict__ wgt,
    signed char* __restrict__ A2, float* __restrict__ scaleA)
{
    __shared__ float sRe[4366];
    __shared__ float sIm[4366];
    __shared__ float mats[NQ][8];
    __shared__ float red[8];
    const int blk = blockIdx.x;
    const int tid = threadIdx.x;
    const int ah = tid >> 4;    // phase A/B: a  | phase C: b
    const int al = tid & 15;    // phase A: b    | phase B/C: c

    if (tid < NQ) {
        float tx = 0.5f * wgt[3 + tid];
        float tz = 0.5f * wgt[15 + tid];
        float c = cosf(tx), s = sinf(tx), cz = cosf(tz), sz = sinf(tz);
        mats[tid][0] =  c * cz;  mats[tid][1] = -c * sz;
        mats[tid][2] =  s * sz;  mats[tid][3] = -s * cz;
        mats[tid][4] = -s * sz;  mats[tid][5] = -s * cz;
        mats[tid][6] =  c * cz;  mats[tid][7] =  c * sz;
    }

    // load 16 consecutive elements (idx = tid*16 + c)
    float xr[16], xi[16];
    {
        const _Float16* pRe = u1 + (size_t)blk * QDIM + tid * 16;
        const _Float16* pIm = u1 + (size_t)(blk + QBATCH) * QDIM + tid * 16;
        f16x8 r0 = ((const f16x8*)pRe)[0], r1 = ((const f16x8*)pRe)[1];
        f16x8 i0 = ((const f16x8*)pIm)[0], i1 = ((const f16x8*)pIm)[1];
#pragma unroll
        for (int j = 0; j < 8; ++j) {
            xr[j] = (float)r0[j]; xr[8 + j] = (float)r1[j];
            xi[j] = (float)i0[j]; xi[8 + j] = (float)i1[j];
        }
    }
    __syncthreads();  // mats ready

#define BFLY_STAGE(arrR, arrI, K_, Q_)                                         \
    {                                                                          \
        const float m00r = mats[Q_][0], m00i = mats[Q_][1];                    \
        const float m01r = mats[Q_][2], m01i = mats[Q_][3];                    \
        const float m10r = mats[Q_][4], m10i = mats[Q_][5];                    \
        const float m11r = mats[Q_][6], m11i = mats[Q_][7];                    \
        _Pragma("unroll")                                                      \
        for (int t = 0; t < 8; ++t) {                                          \
            int i0 = ((t >> (K_)) << ((K_) + 1)) | (t & ((1 << (K_)) - 1));    \
            int i1 = i0 | (1 << (K_));                                         \
            float x0r = arrR[i0], x0i = arrI[i0];                              \
            float x1r = arrR[i1], x1i = arrI[i1];                              \
            arrR[i0] = m00r * x0r - m00i * x0i + m01r * x1r - m01i * x1i;      \
            arrI[i0] = m00r * x0i + m00i * x0r + m01r * x1i + m01i * x1r;      \
            arrR[i1] = m10r * x0r - m10i * x0i + m11r * x1r - m11i * x1i;      \
            arrI[i1] = m10r * x0i + m10i * x0r + m11r * x1i + m11i * x1r;      \
        }                                                                      \
    }

    // Phase A: idx bits 0..3 (c), qubits 11..8
#pragma unroll
    for (int p = 0; p < 4; ++p) BFLY_STAGE(xr, xi, p, 11 - p);

    // Exchange 1: thread (a=ah, b=al) writes its c-line
#pragma unroll
    for (int c = 0; c < 16; ++c) {
        sRe[273 * ah + 17 * al + c] = xr[c];
        sIm[273 * ah + 17 * al + c] = xi[c];
    }
    __syncthreads();

    // Phase B: thread (a=ah, c=al) reads b-line; stages on idx bits 4..7
    float yr[16], yi[16];
#pragma unroll
    for (int b = 0; b < 16; ++b) {
        yr[b] = sRe[273 * ah + 17 * b + al];
        yi[b] = sIm[273 * ah + 17 * b + al];
    }
#pragma unroll
    for (int p = 0; p < 4; ++p) BFLY_STAGE(yr, yi, p, 7 - p);

    // Exchange 2: same positions this thread read — no barrier needed before write
#pragma unroll
    for (int b = 0; b < 16; ++b) {
        sRe[273 * ah + 17 * b + al] = yr[b];
        sIm[273 * ah + 17 * b + al] = yi[b];
    }
    __syncthreads();

    // Phase C: thread (b=ah, c=al) reads a-line; stages on idx bits 8..11
    float zr[16], zi[16];
#pragma unroll
    for (int a = 0; a < 16; ++a) {
        zr[a] = sRe[273 * a + 17 * ah + al];
        zi[a] = sIm[273 * a + 17 * ah + al];
    }
#pragma unroll
    for (int p = 0; p < 4; ++p) BFLY_STAGE(zr, zi, p, 3 - p);

    // per-row absmax from registers
    float mR = 0.f, mI = 0.f;
#pragma unroll
    for (int j = 0; j < 16; ++j) {
        mR = fmaxf(mR, fabsf(zr[j]));
        mI = fmaxf(mI, fabsf(zi[j]));
    }
#pragma unroll
    for (int off = 32; off > 0; off >>= 1) {
        mR = fmaxf(mR, __shfl_xor(mR, off, 64));
        mI = fmaxf(mI, __shfl_xor(mI, off, 64));
    }
    const int wid = tid >> 6;
    if ((tid & 63) == 0) { red[wid] = mR; red[4 + wid] = mI; }
    __syncthreads();
    mR = fmaxf(fmaxf(red[0], red[1]), fmaxf(red[2], red[3]));
    mI = fmaxf(fmaxf(red[4], red[5]), fmaxf(red[6], red[7]));
    mR = fmaxf(mR, 1e-30f);
    mI = fmaxf(mI, 1e-30f);
    if (tid == 0) {
        scaleA[blk] = mR / 127.f;
        scaleA[blk + QBATCH] = mI / 127.f;
    }
    const float invR = 127.f / mR, invI = 127.f / mI;

    // store: element idx = a*256 + ah*16 + al -> per-a instr covers 64
    // consecutive bytes per wave (coalesced byte stores)
    signed char* oRe = A2 + (size_t)blk * QDIM + ah * 16 + al;
    signed char* oIm = A2 + (size_t)(blk + QBATCH) * QDIM + ah * 16 + al;
#pragma unroll
    for (int a = 0; a < 16; ++a) {
        oRe[a * 256] = (signed char)q8(zr[a] * invR);
        oIm[a * 256] = (signed char)q8(zi[a] * invI);
    }
#undef BFLY_STAGE
}

// ---------------------------------------------------------------------------
// GEMM2 (i8, fused reduce): acc[m,n] = sum_k A2[m,k]*G8[n,k] (i32);
// out[m & 2047] += sum_n (acc * scaleA[m] * dqG)^2.  Same tile/swizzle as gemm_f16,
// two mfma_i32_16x16x64_i8 per fragment pair per 128B stage.
// ---------------------------------------------------------------------------
__global__ __launch_bounds__(256) void gemm2_i8(
    const signed char* __restrict__ A, const signed char* __restrict__ B,
    const float* __restrict__ scaleA, float* __restrict__ out)
{
    const int K = QDIM;  // bytes per row
    __shared__ __attribute__((aligned(16))) signed char As[128 * 128];
    __shared__ __attribute__((aligned(16))) signed char Bs[128 * 128];

    const int tid  = threadIdx.x;
    const int wave = tid >> 6;
    const int lane = tid & 63;
    const int bn0 = blockIdx.x * 128;
    const int bm0 = blockIdx.y * 128;
    const int wm = (wave >> 1) * 64;
    const int wn = (wave & 1) * 64;
    const int q = lane >> 4;
    const int r = lane & 15;
    const int rx = r & 7;

    i32x4 acc[4][4];
#pragma unroll
    for (int i = 0; i < 4; ++i)
#pragma unroll
        for (int j = 0; j < 4; ++j) acc[i][j] = (i32x4){0, 0, 0, 0};

    const signed char* gA[4];
    const signed char* gB[4];
    char* lA[4];
    char* lB[4];
#pragma unroll
    for (int n = 0; n < 4; ++n) {
        int c = n * 256 + tid;
        int row = c >> 3;
        int gcol = (c & 7) ^ (row & 7);
        gA[n] = A + (size_t)(bm0 + row) * K + gcol * 16;
        gB[n] = B + (size_t)(bn0 + row) * K + gcol * 16;
        lA[n] = (char*)As + (n * 256 + wave * 64) * 16;
        lB[n] = (char*)Bs + (n * 256 + wave * 64) * 16;
    }

    for (int kk = 0; kk < K; kk += 128) {
#pragma unroll
        for (int n = 0; n < 4; ++n) {
            gld_lds16(gA[n] + kk, lA[n]);
            gld_lds16(gB[n] + kk, lB[n]);
        }
        __syncthreads();

#pragma unroll
        for (int s = 0; s < 2; ++s) {
            i32x4 af[4], bf[4];
#pragma unroll
            for (int i = 0; i < 4; ++i) {
                int row = wm + i * 16 + r;
                af[i] = *(const i32x4*)&As[row * 128 + (((s * 4 + q) ^ rx) * 16)];
            }
#pragma unroll
            for (int j = 0; j < 4; ++j) {
                int row = wn + j * 16 + r;
                bf[j] = *(const i32x4*)&Bs[row * 128 + (((s * 4 + q) ^ rx) * 16)];
            }
#pragma unroll
            for (int i = 0; i < 4; ++i)
#pragma unroll
                for (int j = 0; j < 4; ++j)
                    acc[i][j] = __builtin_amdgcn_mfma_i32_16x16x64_i8(af[i], bf[j], acc[i][j], 0, 0, 0);
        }
        __syncthreads();
    }

    // C/D layout: col = r, row = q*4 + reg. Fused |.|^2 reduce.
    const float dqG = 6.f / 127.f;
#pragma unroll
    for (int i = 0; i < 4; ++i) {
#pragma unroll
        for (int rr = 0; rr < 4; ++rr) {
            const int row = bm0 + wm + i * 16 + q * 4 + rr;
            const float sc = scaleA[row] * dqG;
            float v = 0.f;
#pragma unroll
            for (int j = 0; j < 4; ++j) {
                float t = sc * (float)acc[i][j][rr];
                v = fmaf(t, t, v);
            }
            v += __shfl_xor(v, 1, 64);
            v += __shfl_xor(v, 2, 64);
            v += __shfl_xor(v, 4, 64);
            v += __shfl_xor(v, 8, 64);
            if (r == 0) atomicAdd(&out[row & (QBATCH - 1)], v);
        }
    }
}

// ---------------------------------------------------------------------------
extern "C" void kernel_launch(void* const* d_in, const int* in_sizes, int n_in,
                              void* d_out, int out_size, void* d_ws, size_t ws_size,
                              hipStream_t stream)
{
    const float* inputs = (const float*)d_in[0];   // [2048, 12]
    const float* weight = (const float*)d_in[1];   // [27]
    const float* E      = (const float*)d_in[2];   // [4096, 4096] fp32
    float* out = (float*)d_out;                    // [2048]

    char* ws = (char*)d_ws;
    const size_t MB = 1024 * 1024;
    _Float16*    Eh     = (_Float16*)   (ws + 0);         // 32 MB f16 [4096][4096]
    signed char* G8     = (signed char*)(ws + 32 * MB);   //  8 MB i8  [2048][4096]
    _Float16*    A1     = (_Float16*)   (ws + 40 * MB);   // 32 MB f16 [4096][4096]
    _Float16*    u1     = (_Float16*)   (ws + 72 * MB);   // 32 MB f16 [4096][4096]
    signed char* A2     = (signed char*)(ws + 104 * MB);  // 16 MB i8  [4096][4096]
    float*       scaleA = (float*)      (ws + 120 * MB);  // 16 KB

    conv_kernel<<<(QBATCH * QDIM / 8) / 256, 256, 0, stream>>>(E, weight, Eh, G8);
    expand_kernel<<<QBATCH, 256, 0, stream>>>(inputs, A1, out);
    // u1 = v @ Eh^T  (M=4096 Re/Im stacked, N=4096, K=4096), f16, 256^2 8-phase
    gemm_f16_256<<<dim3(QDIM / 256, QDIM / 256), 512, 0, stream>>>(A1, Eh, u1, QDIM);
    // u2 = R u1 -> int8 rows + per-row scales (3-phase register FFT)
    butterfly_kernel<<<QBATCH, 256, 0, stream>>>(u1, weight, A2, scaleA);
    // out[b] = sum_n |(u2 @ G^T)[b / b+2048, n]|^2  (i8 MFMA, fused reduce)
    gemm2_i8<<<dim3(2048 / 128, QDIM / 128), 256, 0, stream>>>(A2, G8, scaleA, out);
}